// Round 1
// baseline (81.883 us; speedup 1.0000x reference)
//
#include <hip/hip_runtime.h>

#define NEG_SLOPE 0.2f

// ws layout (in floats)
#define OFF_U   0        // 3 layers * 256 (u_src[128] | u_dst[128])
#define OFF_WT  1024     // 3 * 16384 (W transposed: WT[d*128+e] = W[e*128+d])
#define OFF_X1  50176    // 64*128*16  layer-0 output, layout [b][d][16]

__device__ __forceinline__ float lrelu(float z) { return z >= 0.f ? z : NEG_SLOPE * z; }

// ---------------------------------------------------------------------------
// Setup: u vectors (u_s = a_src @ W, u_d = a_dst @ W) and W transposes.
// grid 3 (one block per layer), block 256.
__global__ __launch_bounds__(256) void setup_kernel(
    const float* __restrict__ W0, const float* __restrict__ as0, const float* __restrict__ ad0,
    const float* __restrict__ W1, const float* __restrict__ as1, const float* __restrict__ ad1,
    const float* __restrict__ W2, const float* __restrict__ as2, const float* __restrict__ ad2,
    float* __restrict__ ws) {
  int l = blockIdx.x;
  int tid = threadIdx.x;
  const float* W  = (l == 0) ? W0 : (l == 1) ? W1 : W2;
  const float* av = (tid < 128) ? ((l == 0) ? as0 : (l == 1) ? as1 : as2)
                                : ((l == 0) ? ad0 : (l == 1) ? ad1 : ad2);
  float* u  = ws + OFF_U  + l * 256;
  float* WT = ws + OFF_WT + l * 16384;

  {   // u[tid]: tid<128 -> u_src[d], tid>=128 -> u_dst[d-128]
    int d = tid & 127;
    float acc = 0.f;
    for (int e = 0; e < 128; ++e) acc += av[e] * W[e * 128 + d];
    u[tid] = acc;
  }
  for (int k = 0; k < 64; ++k) {   // transpose 128x128
    int idx = k * 256 + tid;
    int d = idx >> 7, e = idx & 127;
    WT[idx] = W[e * 128 + d];
  }
}

// ---------------------------------------------------------------------------
// Layer 0: one block per (b, patch p of 256 nodes). block 256 = 4 waves.
__global__ __launch_bounds__(256) void l0_kernel(
    const float* __restrict__ x, const int* __restrict__ lengths,
    const float* __restrict__ uvec, const float* __restrict__ WT0,
    const float* __restrict__ b0, float* __restrict__ x1) {
  __shared__ float xs[128 * 260];          // x[d][n], row stride 260 (16B-aligned rows)
  __shared__ float u_sh[256];
  __shared__ float spart[4][256], tpart[4][256];
  __shared__ float sA[256], tA[256];
  __shared__ float am1[256], asf[256], ap1[256];
  __shared__ float w_sh[256];
  __shared__ float xtp[2][128];
  __shared__ float fpart[2][128];

  const int tid  = threadIdx.x;
  const int bid  = blockIdx.x;
  const int b    = bid >> 4;
  const int p    = bid & 15;
  const int lane = tid & 63;
  const int wave = __builtin_amdgcn_readfirstlane(tid >> 6);

  u_sh[tid] = uvec[tid];
  __syncthreads();

  // ---- stage x patch into LDS, fusing s,t partial dot products ----
  const float* xb = x + ((size_t)b * 128) * 4096 + p * 256;
  float s0 = 0.f, s1 = 0.f, s2 = 0.f, s3 = 0.f;
  float t0 = 0.f, t1 = 0.f, t2 = 0.f, t3 = 0.f;
#pragma unroll 8
  for (int it = 0; it < 32; ++it) {
    const int d = it * 4 + wave;
    const float4 v = *(const float4*)(xb + (size_t)d * 4096 + lane * 4);
    const float us = u_sh[d];
    const float ud = u_sh[128 + d];
    s0 += v.x * us; s1 += v.y * us; s2 += v.z * us; s3 += v.w * us;
    t0 += v.x * ud; t1 += v.y * ud; t2 += v.z * ud; t3 += v.w * ud;
    *(float4*)(&xs[d * 260 + lane * 4]) = v;
  }
  {
    const int n4 = lane * 4;
    spart[wave][n4] = s0; spart[wave][n4 + 1] = s1; spart[wave][n4 + 2] = s2; spart[wave][n4 + 3] = s3;
    tpart[wave][n4] = t0; tpart[wave][n4 + 1] = t1; tpart[wave][n4 + 2] = t2; tpart[wave][n4 + 3] = t3;
  }
  __syncthreads();

  {   // combine s,t across the 4 waves (d mod 4 slices)
    const int n = tid;
    sA[n] = spart[0][n] + spart[1][n] + spart[2][n] + spart[3][n];
    tA[n] = tpart[0][n] + tpart[1][n] + tpart[2][n] + tpart[3][n];
  }
  __syncthreads();

  const int len = lengths[b];

  {   // attention per dst j (sources j-1, j, j+1, clamped); fold validity v_j
    const int j = tid;
    const float tj = tA[j];
    const float ls = lrelu(sA[j] + tj);
    const float lm = (j > 0)   ? lrelu(sA[j - 1] + tj) : -1e30f;
    const float lp = (j < 255) ? lrelu(sA[j + 1] + tj) : -1e30f;
    const float mx = fmaxf(ls, fmaxf(lm, lp));
    const float em = (j > 0)   ? __expf(lm - mx) : 0.f;
    const float es = __expf(ls - mx);
    const float ep = (j < 255) ? __expf(lp - mx) : 0.f;
    const float vj = ((p * 256 + j) < len) ? 1.f : 0.f;
    const float sc = vj / (em + es + ep);
    am1[j] = em * sc; asf[j] = es * sc; ap1[j] = ep * sc;
  }
  __syncthreads();

  {   // source-node weights: w[n] = sum over dst j in {n-1,n,n+1} of v_j * alpha(src=n, dst=j)
    const int n = tid;
    float w = asf[n];
    if (n < 255) w += am1[n + 1];
    if (n > 0)   w += ap1[n - 1];
    w_sh[n] = w;
  }
  __syncthreads();

  {   // x~[d] = sum_n w[n] * x[d][n]  (index rotation -> <=2-way LDS banks)
    const int d = tid >> 1, half = tid & 1;
    const int base = half * 128;
    float acc = 0.f;
#pragma unroll 4
    for (int i = 0; i < 128; ++i) {
      const int n = base + ((i + d) & 127);
      acc += w_sh[n] * xs[d * 260 + n];
    }
    xtp[half][d] = acc;
  }
  __syncthreads();

  {   // feat[e] = sum_d x~[d] * W0[e][d]   via transposed WT0 (coalesced)
    const int e = tid & 127, eh = tid >> 7;
    float acc = 0.f;
#pragma unroll 4
    for (int k = 0; k < 64; ++k) {
      const int d = eh * 64 + k;
      const float xt = xtp[0][d] + xtp[1][d];
      acc += xt * WT0[d * 128 + e];
    }
    fpart[eh][e] = acc;
  }
  __syncthreads();

  if (tid < 128) {
    const int e = tid;
    const int rem = len - p * 256;
    const int cnt = rem < 0 ? 0 : (rem > 256 ? 256 : rem);
    float o = 0.f;
    if (cnt > 0) o = (fpart[0][e] + fpart[1][e]) / (float)cnt + b0[e];
    x1[(size_t)(b * 128 + e) * 16 + p] = o;    // layout [b][d][16]
  }
}

// ---------------------------------------------------------------------------
// Fused layers 1+2: one block per (b, p) with p in [0,4); block 128.
// Layer-1 group (b,p) covers positions p*4..p*4+3 of the 16; all masks full.
__global__ __launch_bounds__(128) void l12_kernel(
    const float* __restrict__ x1, const float* __restrict__ u1,
    const float* __restrict__ WT1, const float* __restrict__ b1,
    const float* __restrict__ WT2, const float* __restrict__ b2,
    float* __restrict__ out) {
  __shared__ float xg[128][4];
  __shared__ float stp[8][128];
  __shared__ float sA[4], tA[4], am[4], asf[4], ap[4], w4[4];
  __shared__ float x2l[128];

  const int tid = threadIdx.x;
  const int bid = blockIdx.x;
  const int b = bid >> 2, p = bid & 3;

  const int d = tid;
  const float4 v = *(const float4*)(x1 + (size_t)(b * 128 + d) * 16 + p * 4);
  *(float4*)(&xg[d][0]) = v;
  const float us = u1[d], ud = u1[128 + d];
  stp[0][d] = v.x * us; stp[1][d] = v.y * us; stp[2][d] = v.z * us; stp[3][d] = v.w * us;
  stp[4][d] = v.x * ud; stp[5][d] = v.y * ud; stp[6][d] = v.z * ud; stp[7][d] = v.w * ud;
  __syncthreads();

  if (tid < 8) {
    float acc = 0.f;
    for (int k = 0; k < 128; ++k) acc += stp[tid][k];
    if (tid < 4) sA[tid] = acc; else tA[tid - 4] = acc;
  }
  __syncthreads();

  if (tid < 4) {
    const int j = tid;
    const float tj = tA[j];
    const float ls = lrelu(sA[j] + tj);
    const float lm = (j > 0) ? lrelu(sA[j - 1] + tj) : -1e30f;
    const float lp = (j < 3) ? lrelu(sA[j + 1] + tj) : -1e30f;
    const float mx = fmaxf(ls, fmaxf(lm, lp));
    const float em = (j > 0) ? __expf(lm - mx) : 0.f;
    const float es = __expf(ls - mx);
    const float ep = (j < 3) ? __expf(lp - mx) : 0.f;
    const float sc = 1.f / (em + es + ep);   // all nodes valid in layers 1/2
    am[j] = em * sc; asf[j] = es * sc; ap[j] = ep * sc;
  }
  __syncthreads();

  if (tid < 4) {
    const int n = tid;
    float w = asf[n];
    if (n < 3) w += am[n + 1];
    if (n > 0) w += ap[n - 1];
    w4[n] = w;
  }
  __syncthreads();

  {   // layer-1 feat[e], e = tid; mean over 4 nodes
    const float w0 = w4[0], w1 = w4[1], w2 = w4[2], w3 = w4[3];
    float acc = 0.f;
#pragma unroll 8
    for (int dd = 0; dd < 128; ++dd) {
      const float xt = w0 * xg[dd][0] + w1 * xg[dd][1] + w2 * xg[dd][2] + w3 * xg[dd][3];
      acc += xt * WT1[dd * 128 + tid];
    }
    x2l[tid] = acc * 0.25f + b1[tid];
  }
  __syncthreads();

  {   // layer 2: single self-loop node -> alpha = 1, out = h + b2
    float acc = 0.f;
#pragma unroll 8
    for (int dd = 0; dd < 128; ++dd) acc += x2l[dd] * WT2[dd * 128 + tid];
    out[(size_t)(b * 128 + tid) * 4 + p] = acc + b2[tid];
  }
}

// ---------------------------------------------------------------------------
extern "C" void kernel_launch(void* const* d_in, const int* in_sizes, int n_in,
                              void* d_out, int out_size, void* d_ws, size_t ws_size,
                              hipStream_t stream) {
  (void)in_sizes; (void)n_in; (void)out_size; (void)ws_size;
  const float* x       = (const float*)d_in[0];
  const int*   lengths = (const int*)  d_in[1];
  const float* W0  = (const float*)d_in[2];
  const float* as0 = (const float*)d_in[3];
  const float* ad0 = (const float*)d_in[4];
  const float* b0  = (const float*)d_in[5];
  const float* W1  = (const float*)d_in[6];
  const float* as1 = (const float*)d_in[7];
  const float* ad1 = (const float*)d_in[8];
  const float* b1  = (const float*)d_in[9];
  const float* W2  = (const float*)d_in[10];
  const float* as2 = (const float*)d_in[11];
  const float* ad2 = (const float*)d_in[12];
  const float* b2  = (const float*)d_in[13];
  float* ws  = (float*)d_ws;
  float* out = (float*)d_out;

  setup_kernel<<<3, 256, 0, stream>>>(W0, as0, ad0, W1, as1, ad1, W2, as2, ad2, ws);
  l0_kernel<<<1024, 256, 0, stream>>>(x, lengths, ws + OFF_U, ws + OFF_WT, b0, ws + OFF_X1);
  l12_kernel<<<256, 128, 0, stream>>>(ws + OFF_X1, ws + OFF_U + 256,
                                      ws + OFF_WT + 16384, b1,
                                      ws + OFF_WT + 32768, b2, out);
}

// Round 2
// 67.150 us; speedup vs baseline: 1.2194x; 1.2194x over previous
//
#include <hip/hip_runtime.h>

#define NEG_SLOPE 0.2f

// ws layout (in floats)
#define OFF_U   0        // 3 layers * 256 (u_src[128] | u_dst[128])
#define OFF_WT  1024     // 3 * 16384 (W transposed: WT[d*128+e] = W[e*128+d])
#define OFF_X1  50176    // 64*128*16  layer-0 output, layout [b][d][16]

__device__ __forceinline__ float lrelu(float z) { return z >= 0.f ? z : NEG_SLOPE * z; }

__device__ __forceinline__ unsigned short f2bf(float f) {   // RTNE float->bf16
  unsigned u = __float_as_uint(f);
  u += 0x7FFFu + ((u >> 16) & 1u);
  return (unsigned short)(u >> 16);
}
__device__ __forceinline__ float bf2f(unsigned short s) {
  return __uint_as_float(((unsigned)s) << 16);
}

// ---------------------------------------------------------------------------
// Setup: u vectors (u_s = a_src @ W, u_d = a_dst @ W) and W transposes.
__global__ __launch_bounds__(256) void setup_kernel(
    const float* __restrict__ W0, const float* __restrict__ as0, const float* __restrict__ ad0,
    const float* __restrict__ W1, const float* __restrict__ as1, const float* __restrict__ ad1,
    const float* __restrict__ W2, const float* __restrict__ as2, const float* __restrict__ ad2,
    float* __restrict__ ws) {
  int l = blockIdx.x;
  int tid = threadIdx.x;
  const float* W  = (l == 0) ? W0 : (l == 1) ? W1 : W2;
  const float* av = (tid < 128) ? ((l == 0) ? as0 : (l == 1) ? as1 : as2)
                                : ((l == 0) ? ad0 : (l == 1) ? ad1 : ad2);
  float* u  = ws + OFF_U  + l * 256;
  float* WT = ws + OFF_WT + l * 16384;

  {
    int d = tid & 127;
    float acc = 0.f;
    for (int e = 0; e < 128; ++e) acc += av[e] * W[e * 128 + d];
    u[tid] = acc;
  }
  for (int k = 0; k < 64; ++k) {   // transpose 128x128
    int idx = k * 256 + tid;
    int d = idx >> 7, e = idx & 127;
    WT[idx] = W[e * 128 + d];
  }
}

// ---------------------------------------------------------------------------
// Layer 0: one block per (b, patch p of 256 nodes). block 256 = 4 waves.
// LDS budget 78,848 B -> 2 blocks/CU.
__global__ __launch_bounds__(256) void l0_kernel(
    const float* __restrict__ x, const int* __restrict__ lengths,
    const float* __restrict__ uvec, const float* __restrict__ WT0,
    const float* __restrict__ b0, float* __restrict__ x1) {
  __shared__ unsigned short xs[128 * 264];   // bf16 x[d][n], row stride 264 (8B-mult)
  __shared__ float red[8 * 256];             // spart/tpart -> later am1|asf|ap1|w|xtp|fpart
  __shared__ float sA[256], tA[256];
  __shared__ float u_sh[256];

  const int tid  = threadIdx.x;
  const int bid  = blockIdx.x;
  const int b    = bid >> 4;
  const int p    = bid & 15;
  const int lane = tid & 63;
  const int wave = __builtin_amdgcn_readfirstlane(tid >> 6);

  u_sh[tid] = uvec[tid];
  __syncthreads();

  // ---- stage x patch into LDS (bf16), fusing fp32 s,t partial dots ----
  const float* xb = x + ((size_t)b * 128) * 4096 + p * 256;
  float s0 = 0.f, s1 = 0.f, s2 = 0.f, s3 = 0.f;
  float t0 = 0.f, t1 = 0.f, t2 = 0.f, t3 = 0.f;
#pragma unroll 8
  for (int it = 0; it < 32; ++it) {
    const int d = it * 4 + wave;
    const float4 v = *(const float4*)(xb + (size_t)d * 4096 + lane * 4);
    const float us = u_sh[d];
    const float ud = u_sh[128 + d];
    s0 += v.x * us; s1 += v.y * us; s2 += v.z * us; s3 += v.w * us;
    t0 += v.x * ud; t1 += v.y * ud; t2 += v.z * ud; t3 += v.w * ud;
    ushort4 pk;
    pk.x = f2bf(v.x); pk.y = f2bf(v.y); pk.z = f2bf(v.z); pk.w = f2bf(v.w);
    *(ushort4*)(&xs[d * 264 + lane * 4]) = pk;
  }
  {
    const int n4 = lane * 4;
    *(float4*)(&red[wave * 256 + n4])        = make_float4(s0, s1, s2, s3);
    *(float4*)(&red[1024 + wave * 256 + n4]) = make_float4(t0, t1, t2, t3);
  }
  __syncthreads();

  {   // combine s,t across the 4 waves
    const int n = tid;
    sA[n] = red[n] + red[256 + n] + red[512 + n] + red[768 + n];
    tA[n] = red[1024 + n] + red[1280 + n] + red[1536 + n] + red[1792 + n];
  }
  __syncthreads();

  const int len = lengths[b];

  {   // attention per dst j (sources j-1, j, j+1); fold dst validity v_j
    const int j = tid;
    const float tj = tA[j];
    const float ls = lrelu(sA[j] + tj);
    const float lm = (j > 0)   ? lrelu(sA[j - 1] + tj) : -1e30f;
    const float lp = (j < 255) ? lrelu(sA[j + 1] + tj) : -1e30f;
    const float mx = fmaxf(ls, fmaxf(lm, lp));
    const float em = (j > 0)   ? __expf(lm - mx) : 0.f;
    const float es = __expf(ls - mx);
    const float ep = (j < 255) ? __expf(lp - mx) : 0.f;
    const float vj = ((p * 256 + j) < len) ? 1.f : 0.f;
    const float sc = vj / (em + es + ep);
    red[j] = em * sc;          // am1
    red[256 + j] = es * sc;    // aself
    red[512 + j] = ep * sc;    // ap1
  }
  __syncthreads();

  {   // source weights w[n]
    const int n = tid;
    float w = red[256 + n];
    if (n < 255) w += red[n + 1];
    if (n > 0)   w += red[512 + n - 1];
    red[768 + n] = w;          // w_sh
  }
  __syncthreads();

  {   // x~[d] = sum_n w[n] * x[d][n]; rotated read order -> conflict-free
    const int d = tid >> 1, half = tid & 1;
    float acc = 0.f;
#pragma unroll 8
    for (int j = 0; j < 64; ++j) {
      const int jj = (j + d) & 63;
      const int n  = half * 128 + jj * 2;
      const unsigned pair = *(const unsigned*)(&xs[d * 264 + n]);
      const float f0 = __uint_as_float(pair << 16);
      const float f1 = __uint_as_float(pair & 0xFFFF0000u);
      const float2 w2 = *(const float2*)(&red[768 + n]);
      acc += w2.x * f0 + w2.y * f1;
    }
    red[1024 + half * 128 + d] = acc;   // xtp
  }
  __syncthreads();

  {   // feat[e] = sum_d x~[d] * W0[e][d] via WT0 (coalesced)
    const int e = tid & 127, eh = tid >> 7;
    float acc = 0.f;
#pragma unroll 4
    for (int k = 0; k < 64; ++k) {
      const int d = eh * 64 + k;
      const float xt = red[1024 + d] + red[1152 + d];
      acc += xt * WT0[d * 128 + e];
    }
    red[1280 + eh * 128 + e] = acc;     // fpart
  }
  __syncthreads();

  if (tid < 128) {
    const int e = tid;
    const int rem = len - p * 256;
    const int cnt = rem < 0 ? 0 : (rem > 256 ? 256 : rem);
    float o = 0.f;
    if (cnt > 0) o = (red[1280 + e] + red[1408 + e]) / (float)cnt + b0[e];
    x1[(size_t)(b * 128 + e) * 16 + p] = o;    // layout [b][d][16]
  }
}

// ---------------------------------------------------------------------------
// Fused layers 1+2: one block per (b, p) with p in [0,4); block 128.
__global__ __launch_bounds__(128) void l12_kernel(
    const float* __restrict__ x1, const float* __restrict__ u1,
    const float* __restrict__ WT1, const float* __restrict__ b1,
    const float* __restrict__ WT2, const float* __restrict__ b2,
    float* __restrict__ out) {
  __shared__ float xg[128][4];
  __shared__ float stp[8][128];
  __shared__ float sA[4], tA[4], am[4], asf[4], ap[4], w4[4];
  __shared__ float x2l[128];

  const int tid = threadIdx.x;
  const int bid = blockIdx.x;
  const int b = bid >> 2, p = bid & 3;

  const int d = tid;
  const float4 v = *(const float4*)(x1 + (size_t)(b * 128 + d) * 16 + p * 4);
  *(float4*)(&xg[d][0]) = v;
  const float us = u1[d], ud = u1[128 + d];
  stp[0][d] = v.x * us; stp[1][d] = v.y * us; stp[2][d] = v.z * us; stp[3][d] = v.w * us;
  stp[4][d] = v.x * ud; stp[5][d] = v.y * ud; stp[6][d] = v.z * ud; stp[7][d] = v.w * ud;
  __syncthreads();

  if (tid < 8) {
    float acc = 0.f;
    for (int k = 0; k < 128; ++k) acc += stp[tid][k];
    if (tid < 4) sA[tid] = acc; else tA[tid - 4] = acc;
  }
  __syncthreads();

  if (tid < 4) {
    const int j = tid;
    const float tj = tA[j];
    const float ls = lrelu(sA[j] + tj);
    const float lm = (j > 0) ? lrelu(sA[j - 1] + tj) : -1e30f;
    const float lp = (j < 3) ? lrelu(sA[j + 1] + tj) : -1e30f;
    const float mx = fmaxf(ls, fmaxf(lm, lp));
    const float em = (j > 0) ? __expf(lm - mx) : 0.f;
    const float es = __expf(ls - mx);
    const float ep = (j < 3) ? __expf(lp - mx) : 0.f;
    const float sc = 1.f / (em + es + ep);
    am[j] = em * sc; asf[j] = es * sc; ap[j] = ep * sc;
  }
  __syncthreads();

  if (tid < 4) {
    const int n = tid;
    float w = asf[n];
    if (n < 3) w += am[n + 1];
    if (n > 0) w += ap[n - 1];
    w4[n] = w;
  }
  __syncthreads();

  {   // layer-1 feat[e]
    const float w0 = w4[0], w1 = w4[1], w2 = w4[2], w3 = w4[3];
    float acc = 0.f;
#pragma unroll 8
    for (int dd = 0; dd < 128; ++dd) {
      const float xt = w0 * xg[dd][0] + w1 * xg[dd][1] + w2 * xg[dd][2] + w3 * xg[dd][3];
      acc += xt * WT1[dd * 128 + tid];
    }
    x2l[tid] = acc * 0.25f + b1[tid];
  }
  __syncthreads();

  {   // layer 2: single node, self loop -> alpha=1
    float acc = 0.f;
#pragma unroll 8
    for (int dd = 0; dd < 128; ++dd) acc += x2l[dd] * WT2[dd * 128 + tid];
    out[(size_t)(b * 128 + tid) * 4 + p] = acc + b2[tid];
  }
}

// ---------------------------------------------------------------------------
extern "C" void kernel_launch(void* const* d_in, const int* in_sizes, int n_in,
                              void* d_out, int out_size, void* d_ws, size_t ws_size,
                              hipStream_t stream) {
  (void)in_sizes; (void)n_in; (void)out_size; (void)ws_size;
  const float* x       = (const float*)d_in[0];
  const int*   lengths = (const int*)  d_in[1];
  const float* W0  = (const float*)d_in[2];
  const float* as0 = (const float*)d_in[3];
  const float* ad0 = (const float*)d_in[4];
  const float* b0  = (const float*)d_in[5];
  const float* W1  = (const float*)d_in[6];
  const float* as1 = (const float*)d_in[7];
  const float* ad1 = (const float*)d_in[8];
  const float* b1  = (const float*)d_in[9];
  const float* W2  = (const float*)d_in[10];
  const float* as2 = (const float*)d_in[11];
  const float* ad2 = (const float*)d_in[12];
  const float* b2  = (const float*)d_in[13];
  float* ws  = (float*)d_ws;
  float* out = (float*)d_out;

  setup_kernel<<<3, 256, 0, stream>>>(W0, as0, ad0, W1, as1, ad1, W2, as2, ad2, ws);
  l0_kernel<<<1024, 256, 0, stream>>>(x, lengths, ws + OFF_U, ws + OFF_WT, b0, ws + OFF_X1);
  l12_kernel<<<256, 128, 0, stream>>>(ws + OFF_X1, ws + OFF_U + 256,
                                      ws + OFF_WT + 16384, b1,
                                      ws + OFF_WT + 32768, b2, out);
}

// Round 3
// 56.985 us; speedup vs baseline: 1.4369x; 1.1784x over previous
//
#include <hip/hip_runtime.h>

#define NEG_SLOPE 0.2f

// ws layout (in floats)
#define OFF_U   0        // 3 layers * 256 (u_src[128] | u_dst[128])
#define OFF_WT  1024     // 3 * 16384 (W transposed: WT[d*128+e] = W[e*128+d])
#define OFF_X1  50176    // 64*128*16  layer-0 output, layout [b][d][16]

__device__ __forceinline__ float lrelu(float z) { return z >= 0.f ? z : NEG_SLOPE * z; }

__device__ __forceinline__ unsigned short f2bf(float f) {   // RTNE float->bf16
  unsigned u = __float_as_uint(f);
  u += 0x7FFFu + ((u >> 16) & 1u);
  return (unsigned short)(u >> 16);
}

// ---------------------------------------------------------------------------
// Setup: grid 48 = 3 layers x 16 sub-blocks. LDS-tiled coalesced transpose;
// sub==0 block also computes u vectors (coalesced W columns across lanes).
__global__ __launch_bounds__(256) void setup_kernel(
    const float* __restrict__ W0, const float* __restrict__ as0, const float* __restrict__ ad0,
    const float* __restrict__ W1, const float* __restrict__ as1, const float* __restrict__ ad1,
    const float* __restrict__ W2, const float* __restrict__ as2, const float* __restrict__ ad2,
    float* __restrict__ ws) {
  __shared__ float tile[8][132];
  const int bid = blockIdx.x;
  const int l = bid >> 4, sub = bid & 15;
  const int tid = threadIdx.x;
  const float* W = (l == 0) ? W0 : (l == 1) ? W1 : W2;
  float* WT = ws + OFF_WT + l * 16384;
  const int e0 = sub * 8;

#pragma unroll
  for (int i = 0; i < 4; ++i) {     // read 8 rows of W, coalesced
    const int idx = i * 256 + tid;
    tile[idx >> 7][idx & 127] = W[(e0 + (idx >> 7)) * 128 + (idx & 127)];
  }
  __syncthreads();
#pragma unroll
  for (int i = 0; i < 4; ++i) {     // write transposed
    const int idx = i * 256 + tid;
    const int d = idx >> 3, j = idx & 7;
    WT[d * 128 + e0 + j] = tile[j][d];
  }
  if (sub == 0) {
    const float* av = (tid < 128) ? ((l == 0) ? as0 : (l == 1) ? as1 : as2)
                                  : ((l == 0) ? ad0 : (l == 1) ? ad1 : ad2);
    const int d = tid & 127;
    float acc = 0.f;
#pragma unroll 8
    for (int e = 0; e < 128; ++e) acc += av[e] * W[e * 128 + d];
    ws[OFF_U + l * 256 + tid] = acc;
  }
}

// ---------------------------------------------------------------------------
// Layer 0: one block per (b, patch p of 256 nodes). block 512 = 8 waves.
// LDS 78,848 B -> 2 blocks/CU = 16 waves/CU; launch_bounds caps VGPR at 128.
__global__ __launch_bounds__(512, 4) void l0_kernel(
    const float* __restrict__ x, const int* __restrict__ lengths,
    const float* __restrict__ uvec, const float* __restrict__ WT0,
    const float* __restrict__ b0, float* __restrict__ x1) {
  __shared__ unsigned short xs[128 * 264];   // bf16 x[d][n], row stride 264
  __shared__ float red[2048];                // multi-purpose scratch (8 KB)
  __shared__ float sA[256], tA[256];
  __shared__ float u_sh[256];

  const int tid  = threadIdx.x;
  const int bid  = blockIdx.x;
  const int b    = bid >> 4;
  const int p    = bid & 15;
  const int lane = tid & 63;
  const int wave = __builtin_amdgcn_readfirstlane(tid >> 6);

  if (tid < 256) u_sh[tid] = uvec[tid];
  __syncthreads();

  // ---- stage x patch into LDS (bf16), fusing fp32 s,t partial dots ----
  const float* xb = x + ((size_t)b * 128) * 4096 + p * 256;
  float s0 = 0.f, s1 = 0.f, s2 = 0.f, s3 = 0.f;
  float t0 = 0.f, t1 = 0.f, t2 = 0.f, t3 = 0.f;
#pragma unroll 8
  for (int it = 0; it < 16; ++it) {
    const int d = it * 8 + wave;
    const float4 v = *(const float4*)(xb + (size_t)d * 4096 + lane * 4);
    const float us = u_sh[d];
    const float ud = u_sh[128 + d];
    s0 += v.x * us; s1 += v.y * us; s2 += v.z * us; s3 += v.w * us;
    t0 += v.x * ud; t1 += v.y * ud; t2 += v.z * ud; t3 += v.w * ud;
    ushort4 pk;
    pk.x = f2bf(v.x); pk.y = f2bf(v.y); pk.z = f2bf(v.z); pk.w = f2bf(v.w);
    *(ushort4*)(&xs[d * 264 + lane * 4]) = pk;
  }

  // ---- s,t reduction: 8 wave-partials -> 4 in-place, then 4 -> 1 ----
  const int n4 = lane * 4;
  if (wave >= 4) *(float4*)(&red[(wave - 4) * 256 + n4])   = make_float4(s0, s1, s2, s3);
  else           *(float4*)(&red[1024 + wave * 256 + n4])  = make_float4(t0, t1, t2, t3);
  __syncthreads();
  if (wave < 4) {
    float4 r = *(float4*)(&red[wave * 256 + n4]);
    r.x += s0; r.y += s1; r.z += s2; r.w += s3;
    *(float4*)(&red[wave * 256 + n4]) = r;
  } else {
    float4 r = *(float4*)(&red[1024 + (wave - 4) * 256 + n4]);
    r.x += t0; r.y += t1; r.z += t2; r.w += t3;
    *(float4*)(&red[1024 + (wave - 4) * 256 + n4]) = r;
  }
  __syncthreads();
  if (tid < 256) {
    sA[tid] = red[tid] + red[256 + tid] + red[512 + tid] + red[768 + tid];
  } else {
    const int n = tid - 256;
    tA[n] = red[1024 + n] + red[1280 + n] + red[1536 + n] + red[1792 + n];
  }
  __syncthreads();

  const int len = lengths[b];

  if (tid < 256) {   // attention per dst j; fold dst validity
    const int j = tid;
    const float tj = tA[j];
    const float ls = lrelu(sA[j] + tj);
    const float lm = (j > 0)   ? lrelu(sA[j - 1] + tj) : -1e30f;
    const float lp = (j < 255) ? lrelu(sA[j + 1] + tj) : -1e30f;
    const float mx = fmaxf(ls, fmaxf(lm, lp));
    const float em = (j > 0)   ? __expf(lm - mx) : 0.f;
    const float es = __expf(ls - mx);
    const float ep = (j < 255) ? __expf(lp - mx) : 0.f;
    const float vj = ((p * 256 + j) < len) ? 1.f : 0.f;
    const float sc = vj / (em + es + ep);
    red[j] = em * sc;          // am1
    red[256 + j] = es * sc;    // aself
    red[512 + j] = ep * sc;    // ap1
  }
  __syncthreads();

  if (tid < 256) {   // source weights w[n]
    const int n = tid;
    float w = red[256 + n];
    if (n < 255) w += red[n + 1];
    if (n > 0)   w += red[512 + n - 1];
    red[768 + n] = w;          // w_sh
  }
  __syncthreads();

  {   // x~[d] partials: thread (d, q) sums quarter q; staggered rotation
    const int d = tid >> 2, q = tid & 3;
    float acc = 0.f;
#pragma unroll 8
    for (int j = 0; j < 32; ++j) {
      const int jj = (j + d + q * 8) & 31;
      const int n  = q * 64 + jj * 2;
      const unsigned pair = *(const unsigned*)(&xs[d * 264 + n]);
      const float f0 = __uint_as_float(pair << 16);
      const float f1 = __uint_as_float(pair & 0xFFFF0000u);
      const float2 w2 = *(const float2*)(&red[768 + n]);
      acc += w2.x * f0 + w2.y * f1;
    }
    red[1024 + tid] = acc;
  }
  __syncthreads();

  if (tid < 128) {   // combine 4 quarters -> xtp (reuse sA)
    const float4 r = *(const float4*)(&red[1024 + tid * 4]);
    sA[tid] = r.x + r.y + r.z + r.w;
  }
  __syncthreads();

  {   // feat[e] partials over d-slices via WT0 (coalesced)
    const int e = tid & 127, eh = tid >> 7;
    float acc = 0.f;
#pragma unroll 8
    for (int k = 0; k < 32; ++k) {
      const int d = eh * 32 + k;
      acc += sA[d] * WT0[d * 128 + e];
    }
    red[eh * 128 + e] = acc;
  }
  __syncthreads();

  if (tid < 128) {
    const int e = tid;
    const int rem = len - p * 256;
    const int cnt = rem < 0 ? 0 : (rem > 256 ? 256 : rem);
    float o = 0.f;
    if (cnt > 0)
      o = (red[e] + red[128 + e] + red[256 + e] + red[384 + e]) / (float)cnt + b0[e];
    x1[(size_t)(b * 128 + e) * 16 + p] = o;    // layout [b][d][16]
  }
}

// ---------------------------------------------------------------------------
// Fused layers 1+2: one block per (b, p) with p in [0,4); block 128.
__global__ __launch_bounds__(128) void l12_kernel(
    const float* __restrict__ x1, const float* __restrict__ u1,
    const float* __restrict__ WT1, const float* __restrict__ b1,
    const float* __restrict__ WT2, const float* __restrict__ b2,
    float* __restrict__ out) {
  __shared__ float xg[128][4];
  __shared__ float stp[8][128];
  __shared__ float sA[4], tA[4], am[4], asf[4], ap[4], w4[4];
  __shared__ float x2l[128];

  const int tid = threadIdx.x;
  const int bid = blockIdx.x;
  const int b = bid >> 2, p = bid & 3;

  const int d = tid;
  const float4 v = *(const float4*)(x1 + (size_t)(b * 128 + d) * 16 + p * 4);
  *(float4*)(&xg[d][0]) = v;
  const float us = u1[d], ud = u1[128 + d];
  stp[0][d] = v.x * us; stp[1][d] = v.y * us; stp[2][d] = v.z * us; stp[3][d] = v.w * us;
  stp[4][d] = v.x * ud; stp[5][d] = v.y * ud; stp[6][d] = v.z * ud; stp[7][d] = v.w * ud;
  __syncthreads();

  if (tid < 8) {
    float acc = 0.f;
    for (int k = 0; k < 128; ++k) acc += stp[tid][k];
    if (tid < 4) sA[tid] = acc; else tA[tid - 4] = acc;
  }
  __syncthreads();

  if (tid < 4) {
    const int j = tid;
    const float tj = tA[j];
    const float ls = lrelu(sA[j] + tj);
    const float lm = (j > 0) ? lrelu(sA[j - 1] + tj) : -1e30f;
    const float lp = (j < 3) ? lrelu(sA[j + 1] + tj) : -1e30f;
    const float mx = fmaxf(ls, fmaxf(lm, lp));
    const float em = (j > 0) ? __expf(lm - mx) : 0.f;
    const float es = __expf(ls - mx);
    const float ep = (j < 3) ? __expf(lp - mx) : 0.f;
    const float sc = 1.f / (em + es + ep);
    am[j] = em * sc; asf[j] = es * sc; ap[j] = ep * sc;
  }
  __syncthreads();

  if (tid < 4) {
    const int n = tid;
    float w = asf[n];
    if (n < 3) w += am[n + 1];
    if (n > 0) w += ap[n - 1];
    w4[n] = w;
  }
  __syncthreads();

  {   // layer-1 feat[e]
    const float w0 = w4[0], w1 = w4[1], w2 = w4[2], w3 = w4[3];
    float acc = 0.f;
#pragma unroll 8
    for (int dd = 0; dd < 128; ++dd) {
      const float xt = w0 * xg[dd][0] + w1 * xg[dd][1] + w2 * xg[dd][2] + w3 * xg[dd][3];
      acc += xt * WT1[dd * 128 + tid];
    }
    x2l[tid] = acc * 0.25f + b1[tid];
  }
  __syncthreads();

  {   // layer 2: single node, self loop -> alpha=1
    float acc = 0.f;
#pragma unroll 8
    for (int dd = 0; dd < 128; ++dd) acc += x2l[dd] * WT2[dd * 128 + tid];
    out[(size_t)(b * 128 + tid) * 4 + p] = acc + b2[tid];
  }
}

// ---------------------------------------------------------------------------
extern "C" void kernel_launch(void* const* d_in, const int* in_sizes, int n_in,
                              void* d_out, int out_size, void* d_ws, size_t ws_size,
                              hipStream_t stream) {
  (void)in_sizes; (void)n_in; (void)out_size; (void)ws_size;
  const float* x       = (const float*)d_in[0];
  const int*   lengths = (const int*)  d_in[1];
  const float* W0  = (const float*)d_in[2];
  const float* as0 = (const float*)d_in[3];
  const float* ad0 = (const float*)d_in[4];
  const float* b0  = (const float*)d_in[5];
  const float* W1  = (const float*)d_in[6];
  const float* as1 = (const float*)d_in[7];
  const float* ad1 = (const float*)d_in[8];
  const float* b1  = (const float*)d_in[9];
  const float* W2  = (const float*)d_in[10];
  const float* as2 = (const float*)d_in[11];
  const float* ad2 = (const float*)d_in[12];
  const float* b2  = (const float*)d_in[13];
  float* ws  = (float*)d_ws;
  float* out = (float*)d_out;

  setup_kernel<<<48, 256, 0, stream>>>(W0, as0, ad0, W1, as1, ad1, W2, as2, ad2, ws);
  l0_kernel<<<1024, 512, 0, stream>>>(x, lengths, ws + OFF_U, ws + OFF_WT, b0, ws + OFF_X1);
  l12_kernel<<<256, 128, 0, stream>>>(ws + OFF_X1, ws + OFF_U + 256,
                                      ws + OFF_WT + 16384, b1,
                                      ws + OFF_WT + 32768, b2, out);
}